// Round 1
// baseline (843.691 us; speedup 1.0000x reference)
//
#include <hip/hip_runtime.h>
#include <hip/hip_bf16.h>

#define B_ 16
#define N_ 8192
#define G_ 128
#define K_ 32
#define C_ 384
#define EPSV 1e-5f

typedef __attribute__((ext_vector_type(8))) short bf16x8;
typedef __attribute__((ext_vector_type(8))) unsigned short u16x8;
typedef __attribute__((ext_vector_type(4))) float f32x4;

__device__ __forceinline__ unsigned short f2b(float f){
  unsigned int u = __float_as_uint(f);
  u += 0x7fffu + ((u >> 16) & 1u);      // RNE (no NaNs in this model)
  return (unsigned short)(u >> 16);
}
__device__ __forceinline__ float b2f(unsigned short s){
  return __uint_as_float(((unsigned int)s) << 16);
}
// exact-order squared distance: ((dx*dx + dy*dy) + dz*dz), IEEE, no contraction
__device__ __forceinline__ float sq3(float dx, float dy, float dz){
  return __fadd_rn(__fadd_rn(__fmul_rn(dx,dx), __fmul_rn(dy,dy)), __fmul_rn(dz,dz));
}

// ---------------- weight f32->bf16 pre-conversion ----------------
__global__ __launch_bounds__(256) void prep_kernel(
    const float* __restrict__ w2, const float* __restrict__ w3,
    const float* __restrict__ w4, unsigned short* __restrict__ w2b,
    unsigned short* __restrict__ w3b, unsigned short* __restrict__ w4b){
  int i = blockIdx.x*256 + threadIdx.x;
  if (i < 32768){ w2b[i] = f2b(w2[i]); return; }
  i -= 32768;
  if (i < 262144){ w3b[i] = f2b(w3[i]); return; }
  i -= 262144;
  if (i < 196608){ w4b[i] = f2b(w4[i]); }
}

// ---------------- furthest point sampling (matches jnp scan exactly) ----------------
__global__ __launch_bounds__(1024) void fps_kernel(const float* __restrict__ xyz,
                                                   float* __restrict__ centers){
  const int b = blockIdx.x, t = threadIdx.x;
  const float* xb = xyz + (size_t)b*N_*3;
  __shared__ float sval[16];
  __shared__ int   sidx[16];
  __shared__ int   selS;
  float px[8], py[8], pz[8], dd[8];
  const float p0x = xb[0], p0y = xb[1], p0z = xb[2];
  #pragma unroll
  for (int j = 0; j < 8; j++){
    const int n = t + j*1024;
    px[j] = xb[n*3]; py[j] = xb[n*3+1]; pz[j] = xb[n*3+2];
    dd[j] = sq3(__fsub_rn(px[j],p0x), __fsub_rn(py[j],p0y), __fsub_rn(pz[j],p0z));
  }
  if (t == 0){
    centers[(size_t)b*G_*3 + 0] = p0x;
    centers[(size_t)b*G_*3 + 1] = p0y;
    centers[(size_t)b*G_*3 + 2] = p0z;
  }
  for (int g = 1; g < G_; g++){
    // argmax(dd), ties -> lowest index (jnp.argmax semantics)
    float v = -1.f; int bi = 0;
    #pragma unroll
    for (int j = 0; j < 8; j++){
      const int n = t + j*1024;
      if (dd[j] > v){ v = dd[j]; bi = n; }
    }
    #pragma unroll
    for (int m = 1; m < 64; m <<= 1){
      const float ov = __shfl_xor(v, m);
      const int   oi = __shfl_xor(bi, m);
      if (ov > v || (ov == v && oi < bi)){ v = ov; bi = oi; }
    }
    if ((t & 63) == 0){ sval[t>>6] = v; sidx[t>>6] = bi; }
    __syncthreads();
    if (t == 0){
      float bv = sval[0]; int bb = sidx[0];
      for (int q = 1; q < 16; q++)
        if (sval[q] > bv || (sval[q] == bv && sidx[q] < bb)){ bv = sval[q]; bb = sidx[q]; }
      selS = bb;
      centers[((size_t)b*G_ + g)*3 + 0] = xb[bb*3];
      centers[((size_t)b*G_ + g)*3 + 1] = xb[bb*3+1];
      centers[((size_t)b*G_ + g)*3 + 2] = xb[bb*3+2];
    }
    __syncthreads();
    const int sel = selS;
    const float sx = xb[sel*3], sy = xb[sel*3+1], sz = xb[sel*3+2];
    #pragma unroll
    for (int j = 0; j < 8; j++){
      const float dn = sq3(__fsub_rn(px[j],sx), __fsub_rn(py[j],sy), __fsub_rn(pz[j],sz));
      dd[j] = fminf(dd[j], dn);
    }
  }
}

// ---------------- greedy NN tour over centers (simplified morton) ----------------
__global__ __launch_bounds__(128) void morton_kernel(const float* __restrict__ centers,
                                                     float* __restrict__ centers_ord){
  const int b = blockIdx.x, t = threadIdx.x;
  __shared__ float cx[G_], cy[G_], cz[G_];
  __shared__ float sv[2]; __shared__ int si[2]; __shared__ int selS;
  cx[t] = centers[((size_t)b*G_ + t)*3 + 0];
  cy[t] = centers[((size_t)b*G_ + t)*3 + 1];
  cz[t] = centers[((size_t)b*G_ + t)*3 + 2];
  bool vis = (t == 0);
  if (t == 0){
    centers_ord[(size_t)b*G_*3 + 0] = cx[0];
    centers_ord[(size_t)b*G_*3 + 1] = cy[0];
    centers_ord[(size_t)b*G_*3 + 2] = cz[0];
  }
  __syncthreads();
  float curx = cx[0], cury = cy[0], curz = cz[0];
  for (int step = 1; step < G_; step++){
    float d = sq3(__fsub_rn(cx[t],curx), __fsub_rn(cy[t],cury), __fsub_rn(cz[t],curz));
    if (vis) d = __builtin_inff();
    float v = d; int bi = t;
    #pragma unroll
    for (int m = 1; m < 64; m <<= 1){
      const float ov = __shfl_xor(v, m); const int oi = __shfl_xor(bi, m);
      if (ov < v || (ov == v && oi < bi)){ v = ov; bi = oi; }
    }
    if ((t & 63) == 0){ sv[t>>6] = v; si[t>>6] = bi; }
    __syncthreads();
    if (t == 0){
      float bv = sv[0]; int bb = si[0];
      if (sv[1] < bv || (sv[1] == bv && si[1] < bb)){ bv = sv[1]; bb = si[1]; }
      selS = bb;
      centers_ord[((size_t)b*G_ + step)*3 + 0] = cx[bb];
      centers_ord[((size_t)b*G_ + step)*3 + 1] = cy[bb];
      centers_ord[((size_t)b*G_ + step)*3 + 2] = cz[bb];
    }
    __syncthreads();
    const int cur = selS;
    if (t == cur) vis = true;
    curx = cx[cur]; cury = cy[cur]; curz = cz[cur];
  }
}

// ---------------- KNN (expanded-form d2, top_k tie = lowest index) + recentred gather ----------------
__global__ __launch_bounds__(256) void knn_kernel(const float* __restrict__ xyz,
                                                  const float* __restrict__ centers_ord,
                                                  float* __restrict__ neigh){
  const int gp = blockIdx.x, b = blockIdx.y, t = threadIdx.x;
  __shared__ float d2s[N_];
  __shared__ float sv[4]; __shared__ int si[4]; __shared__ int list[K_];
  const float* xb = xyz + (size_t)b*N_*3;
  const float* cp = centers_ord + ((size_t)b*G_ + gp)*3;
  const float cxv = cp[0], cyv = cp[1], czv = cp[2];
  const float cc = sq3(cxv, cyv, czv);   // (cx*cx+cy*cy)+cz*cz, exact order
  for (int i = 0; i < 32; i++){
    const int n = t + i*256;
    const float x = xb[n*3], y = xb[n*3+1], z = xb[n*3+2];
    const float xx = sq3(x, y, z);
    const float dot = __fadd_rn(__fadd_rn(__fmul_rn(cxv,x), __fmul_rn(cyv,y)), __fmul_rn(czv,z));
    d2s[n] = __fsub_rn(__fadd_rn(cc, xx), __fmul_rn(2.f, dot));
  }
  __syncthreads();
  for (int it = 0; it < K_; it++){
    float v = __builtin_inff(); int bi = N_;
    for (int i = 0; i < 32; i++){
      const int n = t + i*256;
      const float d = d2s[n];
      if (d < v){ v = d; bi = n; }
    }
    #pragma unroll
    for (int m = 1; m < 64; m <<= 1){
      const float ov = __shfl_xor(v, m); const int oi = __shfl_xor(bi, m);
      if (ov < v || (ov == v && oi < bi)){ v = ov; bi = oi; }
    }
    if ((t & 63) == 0){ sv[t>>6] = v; si[t>>6] = bi; }
    __syncthreads();
    if (t == 0){
      float bv = sv[0]; int bb = si[0];
      for (int q = 1; q < 4; q++)
        if (sv[q] < bv || (sv[q] == bv && si[q] < bb)){ bv = sv[q]; bb = si[q]; }
      list[it] = bb;
      d2s[bb] = __builtin_inff();
    }
    __syncthreads();
  }
  if (t < K_*3){
    const int k = t / 3, d = t % 3;
    const int n = list[k];
    neigh[(((size_t)b*G_ + gp)*K_ + k)*3 + d] = __fsub_rn(xb[n*3+d], cp[d]);
  }
}

// ---------------- encoder: L1(VALU) -> L2/L3/L4 (bf16 MFMA) -> maxpool + pos-embed ----------------
__device__ __forceinline__ int swzF(int row, int col){  // [32][256] bf16, XOR swizzle
  int byteo = row*512 + col*2;
  byteo ^= (row & 7) << 4;
  return byteo >> 1;
}
__device__ __forceinline__ int swzA(int row, int col){  // [32][512] bf16
  int byteo = row*1024 + col*2;
  byteo ^= (row & 7) << 4;
  return byteo >> 1;
}

__global__ __launch_bounds__(256) void enc_kernel(
    const float* __restrict__ neigh, const float* __restrict__ centers_ord,
    const float* __restrict__ w1, const float* __restrict__ b1,
    const float* __restrict__ g1, const float* __restrict__ bt1,
    const float* __restrict__ m1, const float* __restrict__ v1,
    const unsigned short* __restrict__ w2b, const float* __restrict__ b2,
    const unsigned short* __restrict__ w3b, const float* __restrict__ b3,
    const float* __restrict__ g3, const float* __restrict__ bt3,
    const float* __restrict__ m3, const float* __restrict__ v3,
    const unsigned short* __restrict__ w4b, const float* __restrict__ b4,
    float* __restrict__ out)
{
  const int gp = blockIdx.x, b = blockIdx.y, t = threadIdx.x;
  const int lane = t & 63, w = t >> 6, lr = lane & 15, lg = lane >> 4;
  __shared__ __align__(16) unsigned short Fl[32*256];  // f (bf16, swizzled); tail reused as tok
  __shared__ __align__(16) unsigned short A3[32*512];  // relu(bn(h@w3+b3)) bf16 swizzled
  __shared__ float pg[96];
  __shared__ float ctr[3];
  __shared__ float fgS[256];
  __shared__ float t3gS[512];
  float* tok = (float*)Fl;  // overlay: Fl is dead once L3 A-frags are in registers

  const int gid = b*G_ + gp;
  if (t < 96) pg[t] = neigh[(size_t)gid*96 + t];
  if (t < 3)  ctr[t] = centers_ord[(size_t)gid*3 + t];
  __syncthreads();

  // ---- L1 (3->128) + BN + ReLU, straight into per-lane MFMA A fragments
  bf16x8 a1f[2][4];
  #pragma unroll
  for (int kt = 0; kt < 4; kt++){
    #pragma unroll
    for (int j = 0; j < 8; j++){
      const int c = kt*32 + lg*8 + j;
      const float wx = w1[c*3], wy = w1[c*3+1], wz = w1[c*3+2];
      const float sc = g1[c] * rsqrtf(v1[c] + EPSV);
      const float mm = m1[c], bb = bt1[c], bc = b1[c];
      #pragma unroll
      for (int mt = 0; mt < 2; mt++){
        const int p = mt*16 + lr;
        float v = pg[p*3]*wx + pg[p*3+1]*wy + pg[p*3+2]*wz + bc;
        v = (v - mm)*sc + bb;
        v = fmaxf(v, 0.f);
        a1f[mt][kt][j] = (short)f2b(v);
      }
    }
  }

  // ---- L2 (128->256): f = a1 @ w2^T + b2   (each wave: 64 output cols)
  f32x4 accB[2][4];
  #pragma unroll
  for (int mt = 0; mt < 2; mt++)
    #pragma unroll
    for (int nt = 0; nt < 4; nt++){
      f32x4 z = {0.f,0.f,0.f,0.f};
      accB[mt][nt] = z;
    }
  const int n0w = w*64;
  #pragma unroll
  for (int nt = 0; nt < 4; nt++){
    #pragma unroll
    for (int kt = 0; kt < 4; kt++){
      const bf16x8 bf = *(const bf16x8*)(w2b + (n0w + nt*16 + lr)*128 + kt*32 + lg*8);
      accB[0][nt] = __builtin_amdgcn_mfma_f32_16x16x32_bf16(a1f[0][kt], bf, accB[0][nt], 0,0,0);
      accB[1][nt] = __builtin_amdgcn_mfma_f32_16x16x32_bf16(a1f[1][kt], bf, accB[1][nt], 0,0,0);
    }
  }
  #pragma unroll
  for (int nt = 0; nt < 4; nt++){
    const int col = n0w + nt*16 + lr;
    const float bc = b2[col];
    #pragma unroll
    for (int mt = 0; mt < 2; mt++)
      #pragma unroll
      for (int r = 0; r < 4; r++){
        const int row = mt*16 + lg*4 + r;
        Fl[swzF(row,col)] = f2b(accB[mt][nt][r] + bc);
      }
  }
  __syncthreads();

  // ---- fg = max_k f  (bf16-monotone, equals bf16(max f32))
  {
    float mx = -__builtin_inff();
    #pragma unroll 4
    for (int row = 0; row < 32; row++) mx = fmaxf(mx, b2f(Fl[swzF(row, t)]));
    fgS[t] = mx;
  }
  __syncthreads();
  // ---- t3g[c] = sum_{j<256} fg[j]*w3[c][j]   (fg half of h@w3^T; identical for all k)
  #pragma unroll
  for (int h = 0; h < 2; h++){
    const int c2 = t + h*256;
    const u16x8* wr = (const u16x8*)(w3b + (size_t)c2*512);
    float s0 = 0.f, s1 = 0.f;
    #pragma unroll 4
    for (int j0 = 0; j0 < 32; j0++){
      const u16x8 wv = wr[j0];
      const float* fp = &fgS[j0*8];
      s0 += fp[0]*b2f(wv[0]); s1 += fp[1]*b2f(wv[1]);
      s0 += fp[2]*b2f(wv[2]); s1 += fp[3]*b2f(wv[3]);
      s0 += fp[4]*b2f(wv[4]); s1 += fp[5]*b2f(wv[5]);
      s0 += fp[6]*b2f(wv[6]); s1 += fp[7]*b2f(wv[7]);
    }
    t3gS[c2] = s0 + s1;
  }
  __syncthreads();

  // ---- L3 (512->512): MFMA on f half + t3g, then BN+ReLU -> A3
  bf16x8 ff[2][8];
  #pragma unroll
  for (int mt = 0; mt < 2; mt++)
    #pragma unroll
    for (int kt = 0; kt < 8; kt++)
      ff[mt][kt] = *(const bf16x8*)&Fl[swzF(mt*16 + lr, kt*32 + lg*8)];
  #pragma unroll
  for (int nt = 0; nt < 8; nt++){
    const int col = w*128 + nt*16 + lr;
    f32x4 a0 = {0.f,0.f,0.f,0.f}, a1v = {0.f,0.f,0.f,0.f};
    const unsigned short* wr = w3b + (size_t)col*512 + 256;
    #pragma unroll
    for (int kt = 0; kt < 8; kt++){
      const bf16x8 bf = *(const bf16x8*)(wr + kt*32 + lg*8);
      a0  = __builtin_amdgcn_mfma_f32_16x16x32_bf16(ff[0][kt], bf, a0, 0,0,0);
      a1v = __builtin_amdgcn_mfma_f32_16x16x32_bf16(ff[1][kt], bf, a1v, 0,0,0);
    }
    const float tg = t3gS[col], bc = b3[col];
    const float sc = g3[col]*rsqrtf(v3[col] + EPSV);
    const float mm = m3[col], bb = bt3[col];
    #pragma unroll
    for (int mt = 0; mt < 2; mt++)
      #pragma unroll
      for (int r = 0; r < 4; r++){
        const int row = mt*16 + lg*4 + r;
        float v = (mt ? a1v[r] : a0[r]) + tg + bc;
        v = (v - mm)*sc + bb;
        v = fmaxf(v, 0.f);
        A3[swzA(row,col)] = f2b(v);
      }
  }
  __syncthreads();

  // ---- L4 (512->384) + max over K + b4 -> tok
  #pragma unroll
  for (int nt = 0; nt < 6; nt++){
    const int col = w*96 + nt*16 + lr;
    f32x4 a0 = {0.f,0.f,0.f,0.f}, a1v = {0.f,0.f,0.f,0.f};
    const unsigned short* wr = w4b + (size_t)col*512;
    #pragma unroll
    for (int kt = 0; kt < 16; kt++){
      const bf16x8 af0 = *(const bf16x8*)&A3[swzA(lr,      kt*32 + lg*8)];
      const bf16x8 af1 = *(const bf16x8*)&A3[swzA(16 + lr, kt*32 + lg*8)];
      const bf16x8 bf  = *(const bf16x8*)(wr + kt*32 + lg*8);
      a0  = __builtin_amdgcn_mfma_f32_16x16x32_bf16(af0, bf, a0, 0,0,0);
      a1v = __builtin_amdgcn_mfma_f32_16x16x32_bf16(af1, bf, a1v, 0,0,0);
    }
    float mx = fmaxf(fmaxf(fmaxf(a0[0],a0[1]), fmaxf(a0[2],a0[3])),
                     fmaxf(fmaxf(a1v[0],a1v[1]), fmaxf(a1v[2],a1v[3])));
    mx = fmaxf(mx, __shfl_xor(mx, 16));
    mx = fmaxf(mx, __shfl_xor(mx, 32));
    if (lg == 0) tok[col] = mx + b4[col];
  }
  __syncthreads();

  // ---- out = tok + pos_embed(center)
  for (int c = t; c < C_; c += 256){
    const int d = c >> 7, r = c & 127, m2 = r >> 1;
    const float e = (float)(2*m2) * (1.f/128.f);
    const float dimt = powf(10000.f, e);
    const float x2 = __fmul_rn(ctr[d], 6.28318530717958647692f);
    const float ang = __fdiv_rn(x2, dimt);
    out[(size_t)gid*C_ + c] = tok[c] + ((r & 1) ? cosf(ang) : sinf(ang));
  }
}

extern "C" void kernel_launch(void* const* d_in, const int* in_sizes, int n_in,
                              void* d_out, int out_size, void* d_ws, size_t ws_size,
                              hipStream_t stream){
  (void)in_sizes; (void)n_in; (void)out_size; (void)ws_size;
  const float* xyz = (const float*)d_in[0];
  const float* w1  = (const float*)d_in[1];
  const float* b1  = (const float*)d_in[2];
  const float* g1  = (const float*)d_in[3];
  const float* bt1 = (const float*)d_in[4];
  const float* m1  = (const float*)d_in[5];
  const float* v1  = (const float*)d_in[6];
  const float* w2  = (const float*)d_in[7];
  const float* b2  = (const float*)d_in[8];
  const float* w3  = (const float*)d_in[9];
  const float* b3  = (const float*)d_in[10];
  const float* g3  = (const float*)d_in[11];
  const float* bt3 = (const float*)d_in[12];
  const float* m3  = (const float*)d_in[13];
  const float* v3  = (const float*)d_in[14];
  const float* w4  = (const float*)d_in[15];
  const float* b4  = (const float*)d_in[16];

  char* ws = (char*)d_ws;
  float* centers      = (float*)ws;                         // 24576 B
  float* centers_ord  = (float*)(ws + 24576);               // 24576 B
  float* neigh        = (float*)(ws + 49152);               // 786432 B
  unsigned short* w2b = (unsigned short*)(ws + 835584);     // 65536 B
  unsigned short* w3b = (unsigned short*)(ws + 901120);     // 524288 B
  unsigned short* w4b = (unsigned short*)(ws + 1425408);    // 393216 B -> total 1818624 B

  prep_kernel  <<<1920, 256, 0, stream>>>(w2, w3, w4, w2b, w3b, w4b);
  fps_kernel   <<<B_, 1024, 0, stream>>>(xyz, centers);
  morton_kernel<<<B_, 128, 0, stream>>>(centers, centers_ord);
  knn_kernel   <<<dim3(G_, B_), 256, 0, stream>>>(xyz, centers_ord, neigh);
  enc_kernel   <<<dim3(G_, B_), 256, 0, stream>>>(neigh, centers_ord,
      w1, b1, g1, bt1, m1, v1, w2b, b2, w3b, b3, g3, bt3, m3, v3, w4b, b4,
      (float*)d_out);
}

// Round 2
// 821.275 us; speedup vs baseline: 1.0273x; 1.0273x over previous
//
#include <hip/hip_runtime.h>
#include <hip/hip_bf16.h>

#define B_ 16
#define N_ 8192
#define G_ 128
#define K_ 32
#define C_ 384
#define EPSV 1e-5f

typedef __attribute__((ext_vector_type(8))) short bf16x8;
typedef __attribute__((ext_vector_type(8))) unsigned short u16x8;
typedef __attribute__((ext_vector_type(4))) float f32x4;

__device__ __forceinline__ unsigned short f2b(float f){
  unsigned int u = __float_as_uint(f);
  u += 0x7fffu + ((u >> 16) & 1u);      // RNE (no NaNs in this model)
  return (unsigned short)(u >> 16);
}
__device__ __forceinline__ float b2f(unsigned short s){
  return __uint_as_float(((unsigned int)s) << 16);
}
// exact-order squared distance: ((dx*dx + dy*dy) + dz*dz), IEEE, no contraction
__device__ __forceinline__ float sq3(float dx, float dy, float dz){
  return __fadd_rn(__fadd_rn(__fmul_rn(dx,dx), __fmul_rn(dy,dy)), __fmul_rn(dz,dz));
}

// ---------------- weight f32->bf16 pre-conversion ----------------
__global__ __launch_bounds__(256) void prep_kernel(
    const float* __restrict__ w2, const float* __restrict__ w3,
    const float* __restrict__ w4, unsigned short* __restrict__ w2b,
    unsigned short* __restrict__ w3b, unsigned short* __restrict__ w4b){
  int i = blockIdx.x*256 + threadIdx.x;
  if (i < 32768){ w2b[i] = f2b(w2[i]); return; }
  i -= 32768;
  if (i < 262144){ w3b[i] = f2b(w3[i]); return; }
  i -= 262144;
  if (i < 196608){ w4b[i] = f2b(w4[i]); }
}

// ---------------- FPS (1 barrier/step, redundant final reduce) + single-wave morton tour ----------------
__global__ __launch_bounds__(1024) void fps_morton_kernel(const float* __restrict__ xyz,
                                                          float* __restrict__ centers_ord){
  const int b = blockIdx.x, t = threadIdx.x, w = t >> 6;
  const float* xb = xyz + (size_t)b*N_*3;
  __shared__ __align__(16) float  sval[2][16];
  __shared__ __align__(16) int    sidx[2][16];
  __shared__ __align__(16) float4 scoord[2][16];
  __shared__ float clx[G_], cly[G_], clz[G_];   // selected centers (FPS order) for morton
  float px[8], py[8], pz[8], dd[8];
  const float p0x = xb[0], p0y = xb[1], p0z = xb[2];
  float v = -1.f; int bi = 0;
  #pragma unroll
  for (int j = 0; j < 8; j++){
    const int n = t + j*1024;
    px[j] = xb[n*3]; py[j] = xb[n*3+1]; pz[j] = xb[n*3+2];
    dd[j] = sq3(__fsub_rn(px[j],p0x), __fsub_rn(py[j],p0y), __fsub_rn(pz[j],p0z));
    if (dd[j] > v){ v = dd[j]; bi = n; }
  }
  if (t == 0){ clx[0] = p0x; cly[0] = p0y; clz[0] = p0z; }
  int buf = 0;
  for (int g = 1; g < G_; g++){
    // in-wave argmax tree on (v,bi); ties -> lowest global index
    #pragma unroll
    for (int m = 1; m < 64; m <<= 1){
      const float ov = __shfl_xor(v, m);
      const int   oi = __shfl_xor(bi, m);
      if (ov > v || (ov == v && oi < bi)){ v = ov; bi = oi; }
    }
    if ((t & 63) == 0){ sval[buf][w] = v; sidx[buf][w] = bi; }
    // owning thread deposits the winner's coordinates (static register indexing)
    if ((bi & 1023) == t){
      #pragma unroll
      for (int j = 0; j < 8; j++)
        if ((bi >> 10) == j){
          float4 c4; c4.x = px[j]; c4.y = py[j]; c4.z = pz[j]; c4.w = 0.f;
          scoord[buf][w] = c4;
        }
    }
    __syncthreads();
    // all threads redundantly reduce the 16 wave candidates (broadcast LDS reads)
    const float4* vp = (const float4*)sval[buf];
    const int4*   ip = (const int4*)sidx[buf];
    const float4 va = vp[0], vb = vp[1], vc = vp[2], vd = vp[3];
    const int4   ia = ip[0], ib = ip[1], ic = ip[2], id_ = ip[3];
    float bv = va.x; int bb = ia.x; int q = 0;
#define UPD(vv, ii, qq) if ((vv) > bv || ((vv) == bv && (ii) < bb)){ bv = (vv); bb = (ii); q = (qq); }
    UPD(va.y, ia.y, 1)  UPD(va.z, ia.z, 2)  UPD(va.w, ia.w, 3)
    UPD(vb.x, ib.x, 4)  UPD(vb.y, ib.y, 5)  UPD(vb.z, ib.z, 6)  UPD(vb.w, ib.w, 7)
    UPD(vc.x, ic.x, 8)  UPD(vc.y, ic.y, 9)  UPD(vc.z, ic.z,10)  UPD(vc.w, ic.w,11)
    UPD(vd.x, id_.x,12) UPD(vd.y, id_.y,13) UPD(vd.z, id_.z,14) UPD(vd.w, id_.w,15)
#undef UPD
    const float4 c = scoord[buf][q];
    if (t == 0){ clx[g] = c.x; cly[g] = c.y; clz[g] = c.z; }
    // fused min-update + next-step argmax
    v = -1.f; bi = 0;
    #pragma unroll
    for (int j = 0; j < 8; j++){
      const float dn = sq3(__fsub_rn(px[j],c.x), __fsub_rn(py[j],c.y), __fsub_rn(pz[j],c.z));
      dd[j] = fminf(dd[j], dn);
      if (dd[j] > v){ v = dd[j]; bi = t + j*1024; }
    }
    buf ^= 1;
  }
  __syncthreads();
  // ---- morton: greedy NN tour, single wave, coords carried through the tree ----
  if (t < 64){
    const int lane = t;
    float mcx[2], mcy[2], mcz[2]; bool mvis[2];
    #pragma unroll
    for (int j = 0; j < 2; j++){
      const int idx = lane + j*64;
      mcx[j] = clx[idx]; mcy[j] = cly[idx]; mcz[j] = clz[idx];
      mvis[j] = (idx == 0);
    }
    float curx = clx[0], cury = cly[0], curz = clz[0];
    if (lane == 0){
      centers_ord[(size_t)b*G_*3 + 0] = curx;
      centers_ord[(size_t)b*G_*3 + 1] = cury;
      centers_ord[(size_t)b*G_*3 + 2] = curz;
    }
    for (int step = 1; step < G_; step++){
      float mv = __builtin_inff(); int mbi = 0;
      float wx = 0.f, wy = 0.f, wz = 0.f;
      #pragma unroll
      for (int j = 0; j < 2; j++){
        float d = sq3(__fsub_rn(mcx[j],curx), __fsub_rn(mcy[j],cury), __fsub_rn(mcz[j],curz));
        if (mvis[j]) d = __builtin_inff();
        const int idx = lane + j*64;
        if (d < mv || (d == mv && idx < mbi)){ mv = d; mbi = idx; wx = mcx[j]; wy = mcy[j]; wz = mcz[j]; }
      }
      #pragma unroll
      for (int m = 1; m < 64; m <<= 1){
        const float ov = __shfl_xor(mv, m);
        const int   oi = __shfl_xor(mbi, m);
        const float ox = __shfl_xor(wx, m);
        const float oy = __shfl_xor(wy, m);
        const float oz = __shfl_xor(wz, m);
        if (ov < mv || (ov == mv && oi < mbi)){ mv = ov; mbi = oi; wx = ox; wy = oy; wz = oz; }
      }
      if ((mbi & 63) == lane){
        #pragma unroll
        for (int j = 0; j < 2; j++)
          if ((mbi >> 6) == j) mvis[j] = true;
      }
      curx = wx; cury = wy; curz = wz;
      if (lane == 0){
        centers_ord[((size_t)b*G_ + step)*3 + 0] = curx;
        centers_ord[((size_t)b*G_ + step)*3 + 1] = cury;
        centers_ord[((size_t)b*G_ + step)*3 + 2] = curz;
      }
    }
  }
}

// ---------------- KNN (expanded-form d2, top_k tie = lowest index) + recentred gather ----------------
__global__ __launch_bounds__(256) void knn_kernel(const float* __restrict__ xyz,
                                                  const float* __restrict__ centers_ord,
                                                  float* __restrict__ neigh){
  const int gp = blockIdx.x, b = blockIdx.y, t = threadIdx.x;
  __shared__ float d2s[N_];
  __shared__ float sv[4]; __shared__ int si[4]; __shared__ int list[K_];
  const float* xb = xyz + (size_t)b*N_*3;
  const float* cp = centers_ord + ((size_t)b*G_ + gp)*3;
  const float cxv = cp[0], cyv = cp[1], czv = cp[2];
  const float cc = sq3(cxv, cyv, czv);   // (cx*cx+cy*cy)+cz*cz, exact order
  for (int i = 0; i < 32; i++){
    const int n = t + i*256;
    const float x = xb[n*3], y = xb[n*3+1], z = xb[n*3+2];
    const float xx = sq3(x, y, z);
    const float dot = __fadd_rn(__fadd_rn(__fmul_rn(cxv,x), __fmul_rn(cyv,y)), __fmul_rn(czv,z));
    d2s[n] = __fsub_rn(__fadd_rn(cc, xx), __fmul_rn(2.f, dot));
  }
  __syncthreads();
  for (int it = 0; it < K_; it++){
    float v = __builtin_inff(); int bi = N_;
    for (int i = 0; i < 32; i++){
      const int n = t + i*256;
      const float d = d2s[n];
      if (d < v){ v = d; bi = n; }
    }
    #pragma unroll
    for (int m = 1; m < 64; m <<= 1){
      const float ov = __shfl_xor(v, m); const int oi = __shfl_xor(bi, m);
      if (ov < v || (ov == v && oi < bi)){ v = ov; bi = oi; }
    }
    if ((t & 63) == 0){ sv[t>>6] = v; si[t>>6] = bi; }
    __syncthreads();
    if (t == 0){
      float bv = sv[0]; int bb = si[0];
      for (int q = 1; q < 4; q++)
        if (sv[q] < bv || (sv[q] == bv && si[q] < bb)){ bv = sv[q]; bb = si[q]; }
      list[it] = bb;
      d2s[bb] = __builtin_inff();
    }
    __syncthreads();
  }
  if (t < K_*3){
    const int k = t / 3, d = t % 3;
    const int n = list[k];
    neigh[(((size_t)b*G_ + gp)*K_ + k)*3 + d] = __fsub_rn(xb[n*3+d], cp[d]);
  }
}

// ---------------- encoder: L1(VALU) -> L2/L3/L4 (bf16 MFMA) -> maxpool + pos-embed ----------------
__device__ __forceinline__ int swzF(int row, int col){  // [32][256] bf16, XOR swizzle
  int byteo = row*512 + col*2;
  byteo ^= (row & 7) << 4;
  return byteo >> 1;
}
__device__ __forceinline__ int swzA(int row, int col){  // [32][512] bf16
  int byteo = row*1024 + col*2;
  byteo ^= (row & 7) << 4;
  return byteo >> 1;
}

__global__ __launch_bounds__(256) void enc_kernel(
    const float* __restrict__ neigh, const float* __restrict__ centers_ord,
    const float* __restrict__ w1, const float* __restrict__ b1,
    const float* __restrict__ g1, const float* __restrict__ bt1,
    const float* __restrict__ m1, const float* __restrict__ v1,
    const unsigned short* __restrict__ w2b, const float* __restrict__ b2,
    const unsigned short* __restrict__ w3b, const float* __restrict__ b3,
    const float* __restrict__ g3, const float* __restrict__ bt3,
    const float* __restrict__ m3, const float* __restrict__ v3,
    const unsigned short* __restrict__ w4b, const float* __restrict__ b4,
    float* __restrict__ out)
{
  const int gp = blockIdx.x, b = blockIdx.y, t = threadIdx.x;
  const int lane = t & 63, w = t >> 6, lr = lane & 15, lg = lane >> 4;
  __shared__ __align__(16) unsigned short Fl[32*256];  // f (bf16, swizzled); tail reused as tok
  __shared__ __align__(16) unsigned short A3[32*512];  // relu(bn(h@w3+b3)) bf16 swizzled
  __shared__ float pg[96];
  __shared__ float ctr[3];
  __shared__ float fgS[256];
  __shared__ float t3gS[512];
  float* tok = (float*)Fl;  // overlay: Fl is dead once L3 A-frags are in registers

  const int gid = b*G_ + gp;
  if (t < 96) pg[t] = neigh[(size_t)gid*96 + t];
  if (t < 3)  ctr[t] = centers_ord[(size_t)gid*3 + t];
  __syncthreads();

  // ---- L1 (3->128) + BN + ReLU, straight into per-lane MFMA A fragments
  bf16x8 a1f[2][4];
  #pragma unroll
  for (int kt = 0; kt < 4; kt++){
    #pragma unroll
    for (int j = 0; j < 8; j++){
      const int c = kt*32 + lg*8 + j;
      const float wx = w1[c*3], wy = w1[c*3+1], wz = w1[c*3+2];
      const float sc = g1[c] * rsqrtf(v1[c] + EPSV);
      const float mm = m1[c], bb = bt1[c], bc = b1[c];
      #pragma unroll
      for (int mt = 0; mt < 2; mt++){
        const int p = mt*16 + lr;
        float v = pg[p*3]*wx + pg[p*3+1]*wy + pg[p*3+2]*wz + bc;
        v = (v - mm)*sc + bb;
        v = fmaxf(v, 0.f);
        a1f[mt][kt][j] = (short)f2b(v);
      }
    }
  }

  // ---- L2 (128->256): f = a1 @ w2^T + b2   (each wave: 64 output cols)
  f32x4 accB[2][4];
  #pragma unroll
  for (int mt = 0; mt < 2; mt++)
    #pragma unroll
    for (int nt = 0; nt < 4; nt++){
      f32x4 z = {0.f,0.f,0.f,0.f};
      accB[mt][nt] = z;
    }
  const int n0w = w*64;
  #pragma unroll
  for (int nt = 0; nt < 4; nt++){
    #pragma unroll
    for (int kt = 0; kt < 4; kt++){
      const bf16x8 bf = *(const bf16x8*)(w2b + (n0w + nt*16 + lr)*128 + kt*32 + lg*8);
      accB[0][nt] = __builtin_amdgcn_mfma_f32_16x16x32_bf16(a1f[0][kt], bf, accB[0][nt], 0,0,0);
      accB[1][nt] = __builtin_amdgcn_mfma_f32_16x16x32_bf16(a1f[1][kt], bf, accB[1][nt], 0,0,0);
    }
  }
  #pragma unroll
  for (int nt = 0; nt < 4; nt++){
    const int col = n0w + nt*16 + lr;
    const float bc = b2[col];
    #pragma unroll
    for (int mt = 0; mt < 2; mt++)
      #pragma unroll
      for (int r = 0; r < 4; r++){
        const int row = mt*16 + lg*4 + r;
        Fl[swzF(row,col)] = f2b(accB[mt][nt][r] + bc);
      }
  }
  __syncthreads();

  // ---- fg = max_k f  (bf16-monotone, equals bf16(max f32))
  {
    float mx = -__builtin_inff();
    #pragma unroll 4
    for (int row = 0; row < 32; row++) mx = fmaxf(mx, b2f(Fl[swzF(row, t)]));
    fgS[t] = mx;
  }
  __syncthreads();
  // ---- t3g[c] = sum_{j<256} fg[j]*w3[c][j]   (fg half of h@w3^T; identical for all k)
  #pragma unroll
  for (int h = 0; h < 2; h++){
    const int c2 = t + h*256;
    const u16x8* wr = (const u16x8*)(w3b + (size_t)c2*512);
    float s0 = 0.f, s1 = 0.f;
    #pragma unroll 4
    for (int j0 = 0; j0 < 32; j0++){
      const u16x8 wv = wr[j0];
      const float* fp = &fgS[j0*8];
      s0 += fp[0]*b2f(wv[0]); s1 += fp[1]*b2f(wv[1]);
      s0 += fp[2]*b2f(wv[2]); s1 += fp[3]*b2f(wv[3]);
      s0 += fp[4]*b2f(wv[4]); s1 += fp[5]*b2f(wv[5]);
      s0 += fp[6]*b2f(wv[6]); s1 += fp[7]*b2f(wv[7]);
    }
    t3gS[c2] = s0 + s1;
  }
  __syncthreads();

  // ---- L3 (512->512): MFMA on f half + t3g, then BN+ReLU -> A3
  bf16x8 ff[2][8];
  #pragma unroll
  for (int mt = 0; mt < 2; mt++)
    #pragma unroll
    for (int kt = 0; kt < 8; kt++)
      ff[mt][kt] = *(const bf16x8*)&Fl[swzF(mt*16 + lr, kt*32 + lg*8)];
  #pragma unroll
  for (int nt = 0; nt < 8; nt++){
    const int col = w*128 + nt*16 + lr;
    f32x4 a0 = {0.f,0.f,0.f,0.f}, a1v = {0.f,0.f,0.f,0.f};
    const unsigned short* wr = w3b + (size_t)col*512 + 256;
    #pragma unroll
    for (int kt = 0; kt < 8; kt++){
      const bf16x8 bf = *(const bf16x8*)(wr + kt*32 + lg*8);
      a0  = __builtin_amdgcn_mfma_f32_16x16x32_bf16(ff[0][kt], bf, a0, 0,0,0);
      a1v = __builtin_amdgcn_mfma_f32_16x16x32_bf16(ff[1][kt], bf, a1v, 0,0,0);
    }
    const float tg = t3gS[col], bc = b3[col];
    const float sc = g3[col]*rsqrtf(v3[col] + EPSV);
    const float mm = m3[col], bb = bt3[col];
    #pragma unroll
    for (int mt = 0; mt < 2; mt++)
      #pragma unroll
      for (int r = 0; r < 4; r++){
        const int row = mt*16 + lg*4 + r;
        float v = (mt ? a1v[r] : a0[r]) + tg + bc;
        v = (v - mm)*sc + bb;
        v = fmaxf(v, 0.f);
        A3[swzA(row,col)] = f2b(v);
      }
  }
  __syncthreads();

  // ---- L4 (512->384) + max over K + b4 -> tok
  #pragma unroll
  for (int nt = 0; nt < 6; nt++){
    const int col = w*96 + nt*16 + lr;
    f32x4 a0 = {0.f,0.f,0.f,0.f}, a1v = {0.f,0.f,0.f,0.f};
    const unsigned short* wr = w4b + (size_t)col*512;
    #pragma unroll
    for (int kt = 0; kt < 16; kt++){
      const bf16x8 af0 = *(const bf16x8*)&A3[swzA(lr,      kt*32 + lg*8)];
      const bf16x8 af1 = *(const bf16x8*)&A3[swzA(16 + lr, kt*32 + lg*8)];
      const bf16x8 bf  = *(const bf16x8*)(wr + kt*32 + lg*8);
      a0  = __builtin_amdgcn_mfma_f32_16x16x32_bf16(af0, bf, a0, 0,0,0);
      a1v = __builtin_amdgcn_mfma_f32_16x16x32_bf16(af1, bf, a1v, 0,0,0);
    }
    float mx = fmaxf(fmaxf(fmaxf(a0[0],a0[1]), fmaxf(a0[2],a0[3])),
                     fmaxf(fmaxf(a1v[0],a1v[1]), fmaxf(a1v[2],a1v[3])));
    mx = fmaxf(mx, __shfl_xor(mx, 16));
    mx = fmaxf(mx, __shfl_xor(mx, 32));
    if (lg == 0) tok[col] = mx + b4[col];
  }
  __syncthreads();

  // ---- out = tok + pos_embed(center)
  for (int c = t; c < C_; c += 256){
    const int d = c >> 7, r = c & 127, m2 = r >> 1;
    const float e = (float)(2*m2) * (1.f/128.f);
    const float dimt = powf(10000.f, e);
    const float x2 = __fmul_rn(ctr[d], 6.28318530717958647692f);
    const float ang = __fdiv_rn(x2, dimt);
    out[(size_t)gid*C_ + c] = tok[c] + ((r & 1) ? cosf(ang) : sinf(ang));
  }
}

extern "C" void kernel_launch(void* const* d_in, const int* in_sizes, int n_in,
                              void* d_out, int out_size, void* d_ws, size_t ws_size,
                              hipStream_t stream){
  (void)in_sizes; (void)n_in; (void)out_size; (void)ws_size;
  const float* xyz = (const float*)d_in[0];
  const float* w1  = (const float*)d_in[1];
  const float* b1  = (const float*)d_in[2];
  const float* g1  = (const float*)d_in[3];
  const float* bt1 = (const float*)d_in[4];
  const float* m1  = (const float*)d_in[5];
  const float* v1  = (const float*)d_in[6];
  const float* w2  = (const float*)d_in[7];
  const float* b2  = (const float*)d_in[8];
  const float* w3  = (const float*)d_in[9];
  const float* b3  = (const float*)d_in[10];
  const float* g3  = (const float*)d_in[11];
  const float* bt3 = (const float*)d_in[12];
  const float* m3  = (const float*)d_in[13];
  const float* v3  = (const float*)d_in[14];
  const float* w4  = (const float*)d_in[15];
  const float* b4  = (const float*)d_in[16];

  char* ws = (char*)d_ws;
  float* centers_ord  = (float*)(ws + 24576);               // 24576 B
  float* neigh        = (float*)(ws + 49152);               // 786432 B
  unsigned short* w2b = (unsigned short*)(ws + 835584);     // 65536 B
  unsigned short* w3b = (unsigned short*)(ws + 901120);     // 524288 B
  unsigned short* w4b = (unsigned short*)(ws + 1425408);    // 393216 B -> total 1818624 B

  prep_kernel      <<<1920, 256, 0, stream>>>(w2, w3, w4, w2b, w3b, w4b);
  fps_morton_kernel<<<B_, 1024, 0, stream>>>(xyz, centers_ord);
  knn_kernel       <<<dim3(G_, B_), 256, 0, stream>>>(xyz, centers_ord, neigh);
  enc_kernel       <<<dim3(G_, B_), 256, 0, stream>>>(neigh, centers_ord,
      w1, b1, g1, bt1, m1, v1, w2b, b2, w3b, b3, g3, bt3, m3, v3, w4b, b4,
      (float*)d_out);
}

// Round 3
// 711.847 us; speedup vs baseline: 1.1852x; 1.1537x over previous
//
#include <hip/hip_runtime.h>
#include <hip/hip_bf16.h>

#define B_ 16
#define N_ 8192
#define G_ 128
#define K_ 32
#define C_ 384
#define EPSV 1e-5f

typedef __attribute__((ext_vector_type(8))) short bf16x8;
typedef __attribute__((ext_vector_type(8))) unsigned short u16x8;
typedef __attribute__((ext_vector_type(4))) float f32x4;

__device__ __forceinline__ unsigned short f2b(float f){
  unsigned int u = __float_as_uint(f);
  u += 0x7fffu + ((u >> 16) & 1u);      // RNE (no NaNs in this model)
  return (unsigned short)(u >> 16);
}
__device__ __forceinline__ float b2f(unsigned short s){
  return __uint_as_float(((unsigned int)s) << 16);
}
// exact-order squared distance: ((dx*dx + dy*dy) + dz*dz), IEEE, no contraction
__device__ __forceinline__ float sq3(float dx, float dy, float dz){
  return __fadd_rn(__fadd_rn(__fmul_rn(dx,dx), __fmul_rn(dy,dy)), __fmul_rn(dz,dz));
}

// ---------------- weight f32->bf16 pre-conversion ----------------
__global__ __launch_bounds__(256) void prep_kernel(
    const float* __restrict__ w2, const float* __restrict__ w3,
    const float* __restrict__ w4, unsigned short* __restrict__ w2b,
    unsigned short* __restrict__ w3b, unsigned short* __restrict__ w4b){
  int i = blockIdx.x*256 + threadIdx.x;
  if (i < 32768){ w2b[i] = f2b(w2[i]); return; }
  i -= 32768;
  if (i < 262144){ w3b[i] = f2b(w3[i]); return; }
  i -= 262144;
  if (i < 196608){ w4b[i] = f2b(w4[i]); }
}

// ---------------- FPS: 256 thr (1 wave/SIMD), 32 pts/thread, 1 barrier/step ----------------
// + single-wave greedy-NN morton tour epilogue
__global__ __launch_bounds__(256) void fps_morton_kernel(const float* __restrict__ xyz,
                                                         float* __restrict__ centers_ord){
  const int b = blockIdx.x, t = threadIdx.x, w = t >> 6;
  const int lane = t & 63;
  const float* xb = xyz + (size_t)b*N_*3;
  __shared__ __align__(16) float sval[2][4];
  __shared__ __align__(16) int   sidx[2][4];
  __shared__ float clx[G_], cly[G_], clz[G_];   // FPS-order centers, for morton
  float px[32], py[32], pz[32], dd[32];
  const float p0x = xb[0], p0y = xb[1], p0z = xb[2];
  float v = -1.f; int jl = 0;
  #pragma unroll
  for (int j = 0; j < 32; j++){
    const int n = t + j*256;
    px[j] = xb[n*3]; py[j] = xb[n*3+1]; pz[j] = xb[n*3+2];
    dd[j] = sq3(__fsub_rn(px[j],p0x), __fsub_rn(py[j],p0y), __fsub_rn(pz[j],p0z));
    if (dd[j] > v){ v = dd[j]; jl = j; }     // jl is inline-const select
  }
  if (t == 0){ clx[0] = p0x; cly[0] = p0y; clz[0] = p0z; }
  int buf = 0;
  for (int g = 1; g < G_; g++){
    int bi = t + jl*256;                      // global index, once per step
    // in-wave argmax tree; ties -> lowest global index (jnp.argmax semantics)
    #pragma unroll
    for (int m = 1; m < 64; m <<= 1){
      const float ov = __shfl_xor(v, m);
      const int   oi = __shfl_xor(bi, m);
      if (ov > v || (ov == v && oi < bi)){ v = ov; bi = oi; }
    }
    if (lane == 0){ sval[buf][w] = v; sidx[buf][w] = bi; }
    __syncthreads();
    // 4-candidate reduce, redundantly by every thread (broadcast reads)
    const float4 vv = *(const float4*)&sval[buf][0];
    const int4   ii = *(const int4*)&sidx[buf][0];
    float bv = vv.x; int bb = ii.x;
    if (vv.y > bv || (vv.y == bv && ii.y < bb)){ bv = vv.y; bb = ii.y; }
    if (vv.z > bv || (vv.z == bv && ii.z < bb)){ bv = vv.z; bb = ii.z; }
    if (vv.w > bv || (vv.w == bv && ii.w < bb)){ bv = vv.w; bb = ii.w; }
    // winner coords: uniform-address global load (xb is L2-resident)
    const float cx = xb[bb*3], cy = xb[bb*3+1], cz = xb[bb*3+2];
    if (t == 0){ clx[g] = cx; cly[g] = cy; clz[g] = cz; }
    // fused min-update + next-step argmax
    v = -1.f; jl = 0;
    #pragma unroll
    for (int j = 0; j < 32; j++){
      const float dn = sq3(__fsub_rn(px[j],cx), __fsub_rn(py[j],cy), __fsub_rn(pz[j],cz));
      dd[j] = fminf(dd[j], dn);
      if (dd[j] > v){ v = dd[j]; jl = j; }
    }
    buf ^= 1;
  }
  __syncthreads();
  // ---- morton: greedy NN tour, single wave, coords carried through the tree ----
  if (t < 64){
    float mcx[2], mcy[2], mcz[2]; bool mvis[2];
    #pragma unroll
    for (int j = 0; j < 2; j++){
      const int idx = lane + j*64;
      mcx[j] = clx[idx]; mcy[j] = cly[idx]; mcz[j] = clz[idx];
      mvis[j] = (idx == 0);
    }
    float curx = clx[0], cury = cly[0], curz = clz[0];
    if (lane == 0){
      centers_ord[(size_t)b*G_*3 + 0] = curx;
      centers_ord[(size_t)b*G_*3 + 1] = cury;
      centers_ord[(size_t)b*G_*3 + 2] = curz;
    }
    for (int step = 1; step < G_; step++){
      float mv = __builtin_inff(); int mbi = 0;
      float wx = 0.f, wy = 0.f, wz = 0.f;
      #pragma unroll
      for (int j = 0; j < 2; j++){
        float d = sq3(__fsub_rn(mcx[j],curx), __fsub_rn(mcy[j],cury), __fsub_rn(mcz[j],curz));
        if (mvis[j]) d = __builtin_inff();
        const int idx = lane + j*64;
        if (d < mv || (d == mv && idx < mbi)){ mv = d; mbi = idx; wx = mcx[j]; wy = mcy[j]; wz = mcz[j]; }
      }
      #pragma unroll
      for (int m = 1; m < 64; m <<= 1){
        const float ov = __shfl_xor(mv, m);
        const int   oi = __shfl_xor(mbi, m);
        const float ox = __shfl_xor(wx, m);
        const float oy = __shfl_xor(wy, m);
        const float oz = __shfl_xor(wz, m);
        if (ov < mv || (ov == mv && oi < mbi)){ mv = ov; mbi = oi; wx = ox; wy = oy; wz = oz; }
      }
      if ((mbi & 63) == lane){
        #pragma unroll
        for (int j = 0; j < 2; j++)
          if ((mbi >> 6) == j) mvis[j] = true;
      }
      curx = wx; cury = wy; curz = wz;
      if (lane == 0){
        centers_ord[((size_t)b*G_ + step)*3 + 0] = curx;
        centers_ord[((size_t)b*G_ + step)*3 + 1] = cury;
        centers_ord[((size_t)b*G_ + step)*3 + 2] = curz;
      }
    }
  }
}

// ---------------- KNN: register-resident d2, winner-only rescan, 1 barrier/iter ----------------
__global__ __launch_bounds__(256) void knn_kernel(const float* __restrict__ xyz,
                                                  const float* __restrict__ centers_ord,
                                                  float* __restrict__ neigh){
  const int gp = blockIdx.x, b = blockIdx.y, t = threadIdx.x;
  const int lane = t & 63, w = t >> 6;
  __shared__ __align__(16) float sv[2][4];
  __shared__ __align__(16) int   si[2][4];
  __shared__ int list[K_];
  const float* xb = xyz + (size_t)b*N_*3;
  const float* cp = centers_ord + ((size_t)b*G_ + gp)*3;
  const float cxv = cp[0], cyv = cp[1], czv = cp[2];
  const float cc = sq3(cxv, cyv, czv);   // (cx*cx+cy*cy)+cz*cz, exact order
  float dd[32];
  float v = __builtin_inff(); int jl = 0;
  #pragma unroll
  for (int j = 0; j < 32; j++){
    const int n = t + j*256;
    const float x = xb[n*3], y = xb[n*3+1], z = xb[n*3+2];
    const float xx = sq3(x, y, z);
    const float dot = __fadd_rn(__fadd_rn(__fmul_rn(cxv,x), __fmul_rn(cyv,y)), __fmul_rn(czv,z));
    dd[j] = __fsub_rn(__fadd_rn(cc, xx), __fmul_rn(2.f, dot));
    if (dd[j] < v){ v = dd[j]; jl = j; }
  }
  int buf = 0;
  for (int it = 0; it < K_; it++){
    float tv = v; int tbi = t + jl*256;
    #pragma unroll
    for (int m = 1; m < 64; m <<= 1){
      const float ov = __shfl_xor(tv, m); const int oi = __shfl_xor(tbi, m);
      if (ov < tv || (ov == tv && oi < tbi)){ tv = ov; tbi = oi; }
    }
    if (lane == 0){ sv[buf][w] = tv; si[buf][w] = tbi; }
    __syncthreads();
    const float4 vv = *(const float4*)&sv[buf][0];
    const int4   ii = *(const int4*)&si[buf][0];
    float bv = vv.x; int bb = ii.x;
    if (vv.y < bv || (vv.y == bv && ii.y < bb)){ bv = vv.y; bb = ii.y; }
    if (vv.z < bv || (vv.z == bv && ii.z < bb)){ bv = vv.z; bb = ii.z; }
    if (vv.w < bv || (vv.w == bv && ii.w < bb)){ bv = vv.w; bb = ii.w; }
    if (t == 0) list[it] = bb;
    if ((bb & 255) == t){
      const int jw = bb >> 8;
      #pragma unroll
      for (int j = 0; j < 32; j++) if (j == jw) dd[j] = __builtin_inff();
      v = __builtin_inff(); jl = 0;
      #pragma unroll
      for (int j = 0; j < 32; j++) if (dd[j] < v){ v = dd[j]; jl = j; }
    }
    buf ^= 1;
  }
  __syncthreads();
  if (t < K_*3){
    const int k = t / 3, d = t % 3;
    const int n = list[k];
    neigh[(((size_t)b*G_ + gp)*K_ + k)*3 + d] = __fsub_rn(xb[n*3+d], cp[d]);
  }
}

// ---------------- encoder: L1(VALU) -> L2/L3/L4 (bf16 MFMA) -> maxpool + pos-embed ----------------
__device__ __forceinline__ int swzF(int row, int col){  // [32][256] bf16, XOR swizzle
  int byteo = row*512 + col*2;
  byteo ^= (row & 7) << 4;
  return byteo >> 1;
}
__device__ __forceinline__ int swzA(int row, int col){  // [32][512] bf16
  int byteo = row*1024 + col*2;
  byteo ^= (row & 7) << 4;
  return byteo >> 1;
}

__global__ __launch_bounds__(256) void enc_kernel(
    const float* __restrict__ neigh, const float* __restrict__ centers_ord,
    const float* __restrict__ w1, const float* __restrict__ b1,
    const float* __restrict__ g1, const float* __restrict__ bt1,
    const float* __restrict__ m1, const float* __restrict__ v1,
    const unsigned short* __restrict__ w2b, const float* __restrict__ b2,
    const unsigned short* __restrict__ w3b, const float* __restrict__ b3,
    const float* __restrict__ g3, const float* __restrict__ bt3,
    const float* __restrict__ m3, const float* __restrict__ v3,
    const unsigned short* __restrict__ w4b, const float* __restrict__ b4,
    float* __restrict__ out)
{
  const int gp = blockIdx.x, b = blockIdx.y, t = threadIdx.x;
  const int lane = t & 63, w = t >> 6, lr = lane & 15, lg = lane >> 4;
  __shared__ __align__(16) unsigned short Fl[32*256];  // f (bf16, swizzled); tail reused as tok
  __shared__ __align__(16) unsigned short A3[32*512];  // relu(bn(h@w3+b3)) bf16 swizzled
  __shared__ float pg[96];
  __shared__ float ctr[3];
  __shared__ float fgS[256];
  __shared__ float t3gS[512];
  float* tok = (float*)Fl;  // overlay: Fl is dead once L3 A-frags are in registers

  const int gid = b*G_ + gp;
  if (t < 96) pg[t] = neigh[(size_t)gid*96 + t];
  if (t < 3)  ctr[t] = centers_ord[(size_t)gid*3 + t];
  __syncthreads();

  // ---- L1 (3->128) + BN + ReLU, straight into per-lane MFMA A fragments
  bf16x8 a1f[2][4];
  #pragma unroll
  for (int kt = 0; kt < 4; kt++){
    #pragma unroll
    for (int j = 0; j < 8; j++){
      const int c = kt*32 + lg*8 + j;
      const float wx = w1[c*3], wy = w1[c*3+1], wz = w1[c*3+2];
      const float sc = g1[c] * rsqrtf(v1[c] + EPSV);
      const float mm = m1[c], bb = bt1[c], bc = b1[c];
      #pragma unroll
      for (int mt = 0; mt < 2; mt++){
        const int p = mt*16 + lr;
        float v = pg[p*3]*wx + pg[p*3+1]*wy + pg[p*3+2]*wz + bc;
        v = (v - mm)*sc + bb;
        v = fmaxf(v, 0.f);
        a1f[mt][kt][j] = (short)f2b(v);
      }
    }
  }

  // ---- L2 (128->256): f = a1 @ w2^T + b2   (each wave: 64 output cols)
  f32x4 accB[2][4];
  #pragma unroll
  for (int mt = 0; mt < 2; mt++)
    #pragma unroll
    for (int nt = 0; nt < 4; nt++){
      f32x4 z = {0.f,0.f,0.f,0.f};
      accB[mt][nt] = z;
    }
  const int n0w = w*64;
  #pragma unroll
  for (int nt = 0; nt < 4; nt++){
    #pragma unroll
    for (int kt = 0; kt < 4; kt++){
      const bf16x8 bf = *(const bf16x8*)(w2b + (n0w + nt*16 + lr)*128 + kt*32 + lg*8);
      accB[0][nt] = __builtin_amdgcn_mfma_f32_16x16x32_bf16(a1f[0][kt], bf, accB[0][nt], 0,0,0);
      accB[1][nt] = __builtin_amdgcn_mfma_f32_16x16x32_bf16(a1f[1][kt], bf, accB[1][nt], 0,0,0);
    }
  }
  #pragma unroll
  for (int nt = 0; nt < 4; nt++){
    const int col = n0w + nt*16 + lr;
    const float bc = b2[col];
    #pragma unroll
    for (int mt = 0; mt < 2; mt++)
      #pragma unroll
      for (int r = 0; r < 4; r++){
        const int row = mt*16 + lg*4 + r;
        Fl[swzF(row,col)] = f2b(accB[mt][nt][r] + bc);
      }
  }
  __syncthreads();

  // ---- fg = max_k f  (bf16-monotone, equals bf16(max f32))
  {
    float mx = -__builtin_inff();
    #pragma unroll 4
    for (int row = 0; row < 32; row++) mx = fmaxf(mx, b2f(Fl[swzF(row, t)]));
    fgS[t] = mx;
  }
  __syncthreads();
  // ---- t3g[c] = sum_{j<256} fg[j]*w3[c][j]   (fg half of h@w3^T; identical for all k)
  #pragma unroll
  for (int h = 0; h < 2; h++){
    const int c2 = t + h*256;
    const u16x8* wr = (const u16x8*)(w3b + (size_t)c2*512);
    float s0 = 0.f, s1 = 0.f;
    #pragma unroll 4
    for (int j0 = 0; j0 < 32; j0++){
      const u16x8 wv = wr[j0];
      const float* fp = &fgS[j0*8];
      s0 += fp[0]*b2f(wv[0]); s1 += fp[1]*b2f(wv[1]);
      s0 += fp[2]*b2f(wv[2]); s1 += fp[3]*b2f(wv[3]);
      s0 += fp[4]*b2f(wv[4]); s1 += fp[5]*b2f(wv[5]);
      s0 += fp[6]*b2f(wv[6]); s1 += fp[7]*b2f(wv[7]);
    }
    t3gS[c2] = s0 + s1;
  }
  __syncthreads();

  // ---- L3 (512->512): MFMA on f half + t3g, then BN+ReLU -> A3
  bf16x8 ff[2][8];
  #pragma unroll
  for (int mt = 0; mt < 2; mt++)
    #pragma unroll
    for (int kt = 0; kt < 8; kt++)
      ff[mt][kt] = *(const bf16x8*)&Fl[swzF(mt*16 + lr, kt*32 + lg*8)];
  #pragma unroll
  for (int nt = 0; nt < 8; nt++){
    const int col = w*128 + nt*16 + lr;
    f32x4 a0 = {0.f,0.f,0.f,0.f}, a1v = {0.f,0.f,0.f,0.f};
    const unsigned short* wr = w3b + (size_t)col*512 + 256;
    #pragma unroll
    for (int kt = 0; kt < 8; kt++){
      const bf16x8 bf = *(const bf16x8*)(wr + kt*32 + lg*8);
      a0  = __builtin_amdgcn_mfma_f32_16x16x32_bf16(ff[0][kt], bf, a0, 0,0,0);
      a1v = __builtin_amdgcn_mfma_f32_16x16x32_bf16(ff[1][kt], bf, a1v, 0,0,0);
    }
    const float tg = t3gS[col], bc = b3[col];
    const float sc = g3[col]*rsqrtf(v3[col] + EPSV);
    const float mm = m3[col], bb = bt3[col];
    #pragma unroll
    for (int mt = 0; mt < 2; mt++)
      #pragma unroll
      for (int r = 0; r < 4; r++){
        const int row = mt*16 + lg*4 + r;
        float v = (mt ? a1v[r] : a0[r]) + tg + bc;
        v = (v - mm)*sc + bb;
        v = fmaxf(v, 0.f);
        A3[swzA(row,col)] = f2b(v);
      }
  }
  __syncthreads();

  // ---- L4 (512->384) + max over K + b4 -> tok
  #pragma unroll
  for (int nt = 0; nt < 6; nt++){
    const int col = w*96 + nt*16 + lr;
    f32x4 a0 = {0.f,0.f,0.f,0.f}, a1v = {0.f,0.f,0.f,0.f};
    const unsigned short* wr = w4b + (size_t)col*512;
    #pragma unroll
    for (int kt = 0; kt < 16; kt++){
      const bf16x8 af0 = *(const bf16x8*)&A3[swzA(lr,      kt*32 + lg*8)];
      const bf16x8 af1 = *(const bf16x8*)&A3[swzA(16 + lr, kt*32 + lg*8)];
      const bf16x8 bf  = *(const bf16x8*)(wr + kt*32 + lg*8);
      a0  = __builtin_amdgcn_mfma_f32_16x16x32_bf16(af0, bf, a0, 0,0,0);
      a1v = __builtin_amdgcn_mfma_f32_16x16x32_bf16(af1, bf, a1v, 0,0,0);
    }
    float mx = fmaxf(fmaxf(fmaxf(a0[0],a0[1]), fmaxf(a0[2],a0[3])),
                     fmaxf(fmaxf(a1v[0],a1v[1]), fmaxf(a1v[2],a1v[3])));
    mx = fmaxf(mx, __shfl_xor(mx, 16));
    mx = fmaxf(mx, __shfl_xor(mx, 32));
    if (lg == 0) tok[col] = mx + b4[col];
  }
  __syncthreads();

  // ---- out = tok + pos_embed(center)
  for (int c = t; c < C_; c += 256){
    const int d = c >> 7, r = c & 127, m2 = r >> 1;
    const float e = (float)(2*m2) * (1.f/128.f);
    const float dimt = powf(10000.f, e);
    const float x2 = __fmul_rn(ctr[d], 6.28318530717958647692f);
    const float ang = __fdiv_rn(x2, dimt);
    out[(size_t)gid*C_ + c] = tok[c] + ((r & 1) ? cosf(ang) : sinf(ang));
  }
}

extern "C" void kernel_launch(void* const* d_in, const int* in_sizes, int n_in,
                              void* d_out, int out_size, void* d_ws, size_t ws_size,
                              hipStream_t stream){
  (void)in_sizes; (void)n_in; (void)out_size; (void)ws_size;
  const float* xyz = (const float*)d_in[0];
  const float* w1  = (const float*)d_in[1];
  const float* b1  = (const float*)d_in[2];
  const float* g1  = (const float*)d_in[3];
  const float* bt1 = (const float*)d_in[4];
  const float* m1  = (const float*)d_in[5];
  const float* v1  = (const float*)d_in[6];
  const float* w2  = (const float*)d_in[7];
  const float* b2  = (const float*)d_in[8];
  const float* w3  = (const float*)d_in[9];
  const float* b3  = (const float*)d_in[10];
  const float* g3  = (const float*)d_in[11];
  const float* bt3 = (const float*)d_in[12];
  const float* m3  = (const float*)d_in[13];
  const float* v3  = (const float*)d_in[14];
  const float* w4  = (const float*)d_in[15];
  const float* b4  = (const float*)d_in[16];

  char* ws = (char*)d_ws;
  float* centers_ord  = (float*)(ws + 24576);               // 24576 B
  float* neigh        = (float*)(ws + 49152);               // 786432 B
  unsigned short* w2b = (unsigned short*)(ws + 835584);     // 65536 B
  unsigned short* w3b = (unsigned short*)(ws + 901120);     // 524288 B
  unsigned short* w4b = (unsigned short*)(ws + 1425408);    // 393216 B -> total 1818624 B

  prep_kernel      <<<1920, 256, 0, stream>>>(w2, w3, w4, w2b, w3b, w4b);
  fps_morton_kernel<<<B_, 256, 0, stream>>>(xyz, centers_ord);
  knn_kernel       <<<dim3(G_, B_), 256, 0, stream>>>(xyz, centers_ord, neigh);
  enc_kernel       <<<dim3(G_, B_), 256, 0, stream>>>(neigh, centers_ord,
      w1, b1, g1, bt1, m1, v1, w2b, b2, w3b, b3, g3, bt3, m3, v3, w4b, b4,
      (float*)d_out);
}

// Round 4
// 681.482 us; speedup vs baseline: 1.2380x; 1.0446x over previous
//
#include <hip/hip_runtime.h>
#include <hip/hip_bf16.h>

#define B_ 16
#define N_ 8192
#define G_ 128
#define K_ 32
#define C_ 384
#define EPSV 1e-5f

typedef __attribute__((ext_vector_type(8))) short bf16x8;
typedef __attribute__((ext_vector_type(8))) unsigned short u16x8;
typedef __attribute__((ext_vector_type(4))) float f32x4;
typedef __attribute__((ext_vector_type(2))) float f32x2;

__device__ __forceinline__ unsigned short f2b(float f){
  unsigned int u = __float_as_uint(f);
  u += 0x7fffu + ((u >> 16) & 1u);      // RNE (no NaNs in this model)
  return (unsigned short)(u >> 16);
}
__device__ __forceinline__ float b2f(unsigned short s){
  return __uint_as_float(((unsigned int)s) << 16);
}
// exact-order squared distance: ((dx*dx + dy*dy) + dz*dz), IEEE, no contraction
__device__ __forceinline__ float sq3(float dx, float dy, float dz){
  return __fadd_rn(__fadd_rn(__fmul_rn(dx,dx), __fmul_rn(dy,dy)), __fmul_rn(dz,dz));
}
__device__ __forceinline__ f32x2 pkmax(f32x2 a, f32x2 b){
  return f32x2{fmaxf(a.x,b.x), fmaxf(a.y,b.y)};
}

// ---------------- weight f32->bf16 pre-conversion ----------------
__global__ __launch_bounds__(256) void prep_kernel(
    const float* __restrict__ w2, const float* __restrict__ w3,
    const float* __restrict__ w4, unsigned short* __restrict__ w2b,
    unsigned short* __restrict__ w3b, unsigned short* __restrict__ w4b){
  int i = blockIdx.x*256 + threadIdx.x;
  if (i < 32768){ w2b[i] = f2b(w2[i]); return; }
  i -= 32768;
  if (i < 262144){ w3b[i] = f2b(w3[i]); return; }
  i -= 262144;
  if (i < 196608){ w4b[i] = f2b(w4[i]); }
}

// ---------------- FPS: 256 thr, packed-f32 update, deferred argmax, 1 barrier/step ----------------
// __launch_bounds__(256,1): 512-VGPR budget -> 128 floats of point state stay in registers (no spill)
__global__ __launch_bounds__(256, 1) void fps_morton_kernel(const float* __restrict__ xyz,
                                                            float* __restrict__ centers_ord){
  const int b = blockIdx.x, t = threadIdx.x, w = t >> 6;
  const int lane = t & 63;
  const float* xb = xyz + (size_t)b*N_*3;
  __shared__ __align__(16) float sval[2][4];
  __shared__ __align__(16) int   sidx[2][4];
  __shared__ float clx[G_], cly[G_], clz[G_];   // FPS-order centers, for morton
  // point p pair (j, j+16): element .x <-> n = t + j*256, .y <-> n = t + (j+16)*256
  f32x2 X[16], Y[16], Z[16], D[16];
  const float p0x = xb[0], p0y = xb[1], p0z = xb[2];
  {
#pragma clang fp contract(off)
    #pragma unroll
    for (int p = 0; p < 16; p++){
      const int n0 = t + p*256, n1 = t + (p+16)*256;
      X[p] = f32x2{xb[n0*3],   xb[n1*3]};
      Y[p] = f32x2{xb[n0*3+1], xb[n1*3+1]};
      Z[p] = f32x2{xb[n0*3+2], xb[n1*3+2]};
      const f32x2 dx = X[p] - p0x, dy = Y[p] - p0y, dz = Z[p] - p0z;
      D[p] = (dx*dx + dy*dy) + dz*dz;
    }
  }
  if (t == 0){ clx[0] = p0x; cly[0] = p0y; clz[0] = p0z; }
  int buf = 0;
  for (int g = 1; g < G_; g++){
    // deferred argmax: value-only max tree, then descending-index equality scan
    f32x2 m0 = pkmax(pkmax(pkmax(D[0],D[1]),pkmax(D[2],D[3])),
                     pkmax(pkmax(D[4],D[5]),pkmax(D[6],D[7])));
    f32x2 m1 = pkmax(pkmax(pkmax(D[8],D[9]),pkmax(D[10],D[11])),
                     pkmax(pkmax(D[12],D[13]),pkmax(D[14],D[15])));
    const f32x2 mm = pkmax(m0, m1);
    float v = fmaxf(mm.x, mm.y);
    int jl = 0;
    #pragma unroll
    for (int p = 15; p >= 0; p--) if (D[p].y == v) jl = p + 16;  // j = 31..16
    #pragma unroll
    for (int p = 15; p >= 0; p--) if (D[p].x == v) jl = p;       // j = 15..0 (lowest wins)
    int bi = t + jl*256;
    // in-wave argmax tree; ties -> lowest global index (jnp.argmax semantics)
    #pragma unroll
    for (int mk = 1; mk < 64; mk <<= 1){
      const float ov = __shfl_xor(v, mk);
      const int   oi = __shfl_xor(bi, mk);
      if (ov > v || (ov == v && oi < bi)){ v = ov; bi = oi; }
    }
    if (lane == 0){ sval[buf][w] = v; sidx[buf][w] = bi; }
    __syncthreads();
    // 4-candidate reduce, redundantly by every thread (broadcast reads)
    const float4 vv = *(const float4*)&sval[buf][0];
    const int4   ii = *(const int4*)&sidx[buf][0];
    float bv = vv.x; int bb = ii.x;
    if (vv.y > bv || (vv.y == bv && ii.y < bb)){ bv = vv.y; bb = ii.y; }
    if (vv.z > bv || (vv.z == bv && ii.z < bb)){ bv = vv.z; bb = ii.z; }
    if (vv.w > bv || (vv.w == bv && ii.w < bb)){ bv = vv.w; bb = ii.w; }
    {
#pragma clang fp contract(off)
      // winner coords: uniform-address global load (xb is L2-resident)
      const float cx = xb[bb*3], cy = xb[bb*3+1], cz = xb[bb*3+2];
      if (t == 0){ clx[g] = cx; cly[g] = cy; clz[g] = cz; }
      #pragma unroll
      for (int p = 0; p < 16; p++){
        const f32x2 dx = X[p] - cx, dy = Y[p] - cy, dz = Z[p] - cz;
        const f32x2 dn = (dx*dx + dy*dy) + dz*dz;
        D[p] = f32x2{fminf(D[p].x, dn.x), fminf(D[p].y, dn.y)};
      }
    }
    buf ^= 1;
  }
  __syncthreads();
  // ---- morton: greedy NN tour, single wave; (v,idx) tree + post-tree coord broadcast ----
  if (t < 64){
    float mcx[2], mcy[2], mcz[2]; bool mvis[2];
    #pragma unroll
    for (int j = 0; j < 2; j++){
      const int idx = lane + j*64;
      mcx[j] = clx[idx]; mcy[j] = cly[idx]; mcz[j] = clz[idx];
      mvis[j] = (idx == 0);
    }
    float curx = clx[0], cury = cly[0], curz = clz[0];
    if (lane == 0){
      centers_ord[(size_t)b*G_*3 + 0] = curx;
      centers_ord[(size_t)b*G_*3 + 1] = cury;
      centers_ord[(size_t)b*G_*3 + 2] = curz;
    }
    for (int step = 1; step < G_; step++){
      float mv; int mbi;
      {
        const float d0r = sq3(__fsub_rn(mcx[0],curx), __fsub_rn(mcy[0],cury), __fsub_rn(mcz[0],curz));
        const float d1r = sq3(__fsub_rn(mcx[1],curx), __fsub_rn(mcy[1],cury), __fsub_rn(mcz[1],curz));
        const float d0 = mvis[0] ? __builtin_inff() : d0r;
        const float d1 = mvis[1] ? __builtin_inff() : d1r;
        // lane index < lane+64 always: ties prefer slot 0
        mv = d0; mbi = lane;
        if (d1 < mv){ mv = d1; mbi = lane + 64; }
      }
      #pragma unroll
      for (int mk = 1; mk < 64; mk <<= 1){
        const float ov = __shfl_xor(mv, mk);
        const int   oi = __shfl_xor(mbi, mk);
        if (ov < mv || (ov == mv && oi < mbi)){ mv = ov; mbi = oi; }
      }
      // post-tree: winner lane broadcasts its coords (mbi is wave-uniform)
      const int wj = mbi >> 6, wl = mbi & 63;
      const float sx = wj ? mcx[1] : mcx[0];
      const float sy = wj ? mcy[1] : mcy[0];
      const float sz = wj ? mcz[1] : mcz[0];
      curx = __shfl(sx, wl); cury = __shfl(sy, wl); curz = __shfl(sz, wl);
      if (wl == lane){
        if (wj == 0) mvis[0] = true; else mvis[1] = true;
      }
      if (lane == 0){
        centers_ord[((size_t)b*G_ + step)*3 + 0] = curx;
        centers_ord[((size_t)b*G_ + step)*3 + 1] = cury;
        centers_ord[((size_t)b*G_ + step)*3 + 2] = curz;
      }
    }
  }
}

// ---------------- KNN: register-resident d2, winner-only rescan, 1 barrier/iter ----------------
__global__ __launch_bounds__(256, 2) void knn_kernel(const float* __restrict__ xyz,
                                                     const float* __restrict__ centers_ord,
                                                     float* __restrict__ neigh){
  const int gp = blockIdx.x, b = blockIdx.y, t = threadIdx.x;
  const int lane = t & 63, w = t >> 6;
  __shared__ __align__(16) float sv[2][4];
  __shared__ __align__(16) int   si[2][4];
  __shared__ int list[K_];
  const float* xb = xyz + (size_t)b*N_*3;
  const float* cp = centers_ord + ((size_t)b*G_ + gp)*3;
  const float cxv = cp[0], cyv = cp[1], czv = cp[2];
  const float cc = sq3(cxv, cyv, czv);   // (cx*cx+cy*cy)+cz*cz, exact order
  float dd[32];
  float v = __builtin_inff(); int jl = 0;
  #pragma unroll
  for (int j = 0; j < 32; j++){
    const int n = t + j*256;
    const float x = xb[n*3], y = xb[n*3+1], z = xb[n*3+2];
    const float xx = sq3(x, y, z);
    const float dot = __fadd_rn(__fadd_rn(__fmul_rn(cxv,x), __fmul_rn(cyv,y)), __fmul_rn(czv,z));
    dd[j] = __fsub_rn(__fadd_rn(cc, xx), __fmul_rn(2.f, dot));
    if (dd[j] < v){ v = dd[j]; jl = j; }
  }
  int buf = 0;
  for (int it = 0; it < K_; it++){
    float tv = v; int tbi = t + jl*256;
    #pragma unroll
    for (int m = 1; m < 64; m <<= 1){
      const float ov = __shfl_xor(tv, m); const int oi = __shfl_xor(tbi, m);
      if (ov < tv || (ov == tv && oi < tbi)){ tv = ov; tbi = oi; }
    }
    if (lane == 0){ sv[buf][w] = tv; si[buf][w] = tbi; }
    __syncthreads();
    const float4 vv = *(const float4*)&sv[buf][0];
    const int4   ii = *(const int4*)&si[buf][0];
    float bv = vv.x; int bb = ii.x;
    if (vv.y < bv || (vv.y == bv && ii.y < bb)){ bv = vv.y; bb = ii.y; }
    if (vv.z < bv || (vv.z == bv && ii.z < bb)){ bv = vv.z; bb = ii.z; }
    if (vv.w < bv || (vv.w == bv && ii.w < bb)){ bv = vv.w; bb = ii.w; }
    if (t == 0) list[it] = bb;
    if ((bb & 255) == t){
      const int jw = bb >> 8;
      #pragma unroll
      for (int j = 0; j < 32; j++) if (j == jw) dd[j] = __builtin_inff();
      v = __builtin_inff(); jl = 0;
      #pragma unroll
      for (int j = 0; j < 32; j++) if (dd[j] < v){ v = dd[j]; jl = j; }
    }
    buf ^= 1;
  }
  __syncthreads();
  if (t < K_*3){
    const int k = t / 3, d = t % 3;
    const int n = list[k];
    neigh[(((size_t)b*G_ + gp)*K_ + k)*3 + d] = __fsub_rn(xb[n*3+d], cp[d]);
  }
}

// ---------------- encoder: L1(VALU) -> L2/L3/L4 (bf16 MFMA) -> maxpool + pos-embed ----------------
__device__ __forceinline__ int swzF(int row, int col){  // [32][256] bf16, XOR swizzle
  int byteo = row*512 + col*2;
  byteo ^= (row & 7) << 4;
  return byteo >> 1;
}
__device__ __forceinline__ int swzA(int row, int col){  // [32][512] bf16
  int byteo = row*1024 + col*2;
  byteo ^= (row & 7) << 4;
  return byteo >> 1;
}

__global__ __launch_bounds__(256, 2) void enc_kernel(
    const float* __restrict__ neigh, const float* __restrict__ centers_ord,
    const float* __restrict__ w1, const float* __restrict__ b1,
    const float* __restrict__ g1, const float* __restrict__ bt1,
    const float* __restrict__ m1, const float* __restrict__ v1,
    const unsigned short* __restrict__ w2b, const float* __restrict__ b2,
    const unsigned short* __restrict__ w3b, const float* __restrict__ b3,
    const float* __restrict__ g3, const float* __restrict__ bt3,
    const float* __restrict__ m3, const float* __restrict__ v3,
    const unsigned short* __restrict__ w4b, const float* __restrict__ b4,
    float* __restrict__ out)
{
  const int gp = blockIdx.x, b = blockIdx.y, t = threadIdx.x;
  const int lane = t & 63, w = t >> 6, lr = lane & 15, lg = lane >> 4;
  __shared__ __align__(16) unsigned short Fl[32*256];  // f (bf16, swizzled); tail reused as tok
  __shared__ __align__(16) unsigned short A3[32*512];  // relu(bn(h@w3+b3)) bf16 swizzled
  __shared__ float pg[96];
  __shared__ float ctr[3];
  __shared__ float fgS[256];
  __shared__ float t3gS[512];
  float* tok = (float*)Fl;  // overlay: Fl is dead once L3 A-frags are in registers

  const int gid = b*G_ + gp;
  if (t < 96) pg[t] = neigh[(size_t)gid*96 + t];
  if (t < 3)  ctr[t] = centers_ord[(size_t)gid*3 + t];
  __syncthreads();

  // ---- L1 (3->128) + BN + ReLU, straight into per-lane MFMA A fragments
  bf16x8 a1f[2][4];
  #pragma unroll
  for (int kt = 0; kt < 4; kt++){
    #pragma unroll
    for (int j = 0; j < 8; j++){
      const int c = kt*32 + lg*8 + j;
      const float wx = w1[c*3], wy = w1[c*3+1], wz = w1[c*3+2];
      const float sc = g1[c] * rsqrtf(v1[c] + EPSV);
      const float mm = m1[c], bb = bt1[c], bc = b1[c];
      #pragma unroll
      for (int mt = 0; mt < 2; mt++){
        const int p = mt*16 + lr;
        float v = pg[p*3]*wx + pg[p*3+1]*wy + pg[p*3+2]*wz + bc;
        v = (v - mm)*sc + bb;
        v = fmaxf(v, 0.f);
        a1f[mt][kt][j] = (short)f2b(v);
      }
    }
  }

  // ---- L2 (128->256): f = a1 @ w2^T + b2   (each wave: 64 output cols)
  f32x4 accB[2][4];
  #pragma unroll
  for (int mt = 0; mt < 2; mt++)
    #pragma unroll
    for (int nt = 0; nt < 4; nt++){
      f32x4 z = {0.f,0.f,0.f,0.f};
      accB[mt][nt] = z;
    }
  const int n0w = w*64;
  #pragma unroll
  for (int nt = 0; nt < 4; nt++){
    #pragma unroll
    for (int kt = 0; kt < 4; kt++){
      const bf16x8 bf = *(const bf16x8*)(w2b + (n0w + nt*16 + lr)*128 + kt*32 + lg*8);
      accB[0][nt] = __builtin_amdgcn_mfma_f32_16x16x32_bf16(a1f[0][kt], bf, accB[0][nt], 0,0,0);
      accB[1][nt] = __builtin_amdgcn_mfma_f32_16x16x32_bf16(a1f[1][kt], bf, accB[1][nt], 0,0,0);
    }
  }
  #pragma unroll
  for (int nt = 0; nt < 4; nt++){
    const int col = n0w + nt*16 + lr;
    const float bc = b2[col];
    #pragma unroll
    for (int mt = 0; mt < 2; mt++)
      #pragma unroll
      for (int r = 0; r < 4; r++){
        const int row = mt*16 + lg*4 + r;
        Fl[swzF(row,col)] = f2b(accB[mt][nt][r] + bc);
      }
  }
  __syncthreads();

  // ---- fg = max_k f  (bf16-monotone, equals bf16(max f32))
  {
    float mx = -__builtin_inff();
    #pragma unroll 4
    for (int row = 0; row < 32; row++) mx = fmaxf(mx, b2f(Fl[swzF(row, t)]));
    fgS[t] = mx;
  }
  __syncthreads();
  // ---- t3g[c] = sum_{j<256} fg[j]*w3[c][j]   (fg half of h@w3^T; identical for all k)
  #pragma unroll
  for (int h = 0; h < 2; h++){
    const int c2 = t + h*256;
    const u16x8* wr = (const u16x8*)(w3b + (size_t)c2*512);
    float s0 = 0.f, s1 = 0.f;
    #pragma unroll 4
    for (int j0 = 0; j0 < 32; j0++){
      const u16x8 wv = wr[j0];
      const float* fp = &fgS[j0*8];
      s0 += fp[0]*b2f(wv[0]); s1 += fp[1]*b2f(wv[1]);
      s0 += fp[2]*b2f(wv[2]); s1 += fp[3]*b2f(wv[3]);
      s0 += fp[4]*b2f(wv[4]); s1 += fp[5]*b2f(wv[5]);
      s0 += fp[6]*b2f(wv[6]); s1 += fp[7]*b2f(wv[7]);
    }
    t3gS[c2] = s0 + s1;
  }
  __syncthreads();

  // ---- L3 (512->512): MFMA on f half + t3g, then BN+ReLU -> A3
  bf16x8 ff[2][8];
  #pragma unroll
  for (int mt = 0; mt < 2; mt++)
    #pragma unroll
    for (int kt = 0; kt < 8; kt++)
      ff[mt][kt] = *(const bf16x8*)&Fl[swzF(mt*16 + lr, kt*32 + lg*8)];
  #pragma unroll
  for (int nt = 0; nt < 8; nt++){
    const int col = w*128 + nt*16 + lr;
    f32x4 a0 = {0.f,0.f,0.f,0.f}, a1v = {0.f,0.f,0.f,0.f};
    const unsigned short* wr = w3b + (size_t)col*512 + 256;
    #pragma unroll
    for (int kt = 0; kt < 8; kt++){
      const bf16x8 bf = *(const bf16x8*)(wr + kt*32 + lg*8);
      a0  = __builtin_amdgcn_mfma_f32_16x16x32_bf16(ff[0][kt], bf, a0, 0,0,0);
      a1v = __builtin_amdgcn_mfma_f32_16x16x32_bf16(ff[1][kt], bf, a1v, 0,0,0);
    }
    const float tg = t3gS[col], bc = b3[col];
    const float sc = g3[col]*rsqrtf(v3[col] + EPSV);
    const float mm = m3[col], bb = bt3[col];
    #pragma unroll
    for (int mt = 0; mt < 2; mt++)
      #pragma unroll
      for (int r = 0; r < 4; r++){
        const int row = mt*16 + lg*4 + r;
        float v = (mt ? a1v[r] : a0[r]) + tg + bc;
        v = (v - mm)*sc + bb;
        v = fmaxf(v, 0.f);
        A3[swzA(row,col)] = f2b(v);
      }
  }
  __syncthreads();

  // ---- L4 (512->384) + max over K + b4 -> tok
  #pragma unroll
  for (int nt = 0; nt < 6; nt++){
    const int col = w*96 + nt*16 + lr;
    f32x4 a0 = {0.f,0.f,0.f,0.f}, a1v = {0.f,0.f,0.f,0.f};
    const unsigned short* wr = w4b + (size_t)col*512;
    #pragma unroll
    for (int kt = 0; kt < 16; kt++){
      const bf16x8 af0 = *(const bf16x8*)&A3[swzA(lr,      kt*32 + lg*8)];
      const bf16x8 af1 = *(const bf16x8*)&A3[swzA(16 + lr, kt*32 + lg*8)];
      const bf16x8 bf  = *(const bf16x8*)(wr + kt*32 + lg*8);
      a0  = __builtin_amdgcn_mfma_f32_16x16x32_bf16(af0, bf, a0, 0,0,0);
      a1v = __builtin_amdgcn_mfma_f32_16x16x32_bf16(af1, bf, a1v, 0,0,0);
    }
    float mx = fmaxf(fmaxf(fmaxf(a0[0],a0[1]), fmaxf(a0[2],a0[3])),
                     fmaxf(fmaxf(a1v[0],a1v[1]), fmaxf(a1v[2],a1v[3])));
    mx = fmaxf(mx, __shfl_xor(mx, 16));
    mx = fmaxf(mx, __shfl_xor(mx, 32));
    if (lg == 0) tok[col] = mx + b4[col];
  }
  __syncthreads();

  // ---- out = tok + pos_embed(center)
  for (int c = t; c < C_; c += 256){
    const int d = c >> 7, r = c & 127, m2 = r >> 1;
    const float e = (float)(2*m2) * (1.f/128.f);
    const float dimt = powf(10000.f, e);
    const float x2 = __fmul_rn(ctr[d], 6.28318530717958647692f);
    const float ang = __fdiv_rn(x2, dimt);
    out[(size_t)gid*C_ + c] = tok[c] + ((r & 1) ? cosf(ang) : sinf(ang));
  }
}

extern "C" void kernel_launch(void* const* d_in, const int* in_sizes, int n_in,
                              void* d_out, int out_size, void* d_ws, size_t ws_size,
                              hipStream_t stream){
  (void)in_sizes; (void)n_in; (void)out_size; (void)ws_size;
  const float* xyz = (const float*)d_in[0];
  const float* w1  = (const float*)d_in[1];
  const float* b1  = (const float*)d_in[2];
  const float* g1  = (const float*)d_in[3];
  const float* bt1 = (const float*)d_in[4];
  const float* m1  = (const float*)d_in[5];
  const float* v1  = (const float*)d_in[6];
  const float* w2  = (const float*)d_in[7];
  const float* b2  = (const float*)d_in[8];
  const float* w3  = (const float*)d_in[9];
  const float* b3  = (const float*)d_in[10];
  const float* g3  = (const float*)d_in[11];
  const float* bt3 = (const float*)d_in[12];
  const float* m3  = (const float*)d_in[13];
  const float* v3  = (const float*)d_in[14];
  const float* w4  = (const float*)d_in[15];
  const float* b4  = (const float*)d_in[16];

  char* ws = (char*)d_ws;
  float* centers_ord  = (float*)(ws + 24576);               // 24576 B
  float* neigh        = (float*)(ws + 49152);               // 786432 B
  unsigned short* w2b = (unsigned short*)(ws + 835584);     // 65536 B
  unsigned short* w3b = (unsigned short*)(ws + 901120);     // 524288 B
  unsigned short* w4b = (unsigned short*)(ws + 1425408);    // 393216 B -> total 1818624 B

  prep_kernel      <<<1920, 256, 0, stream>>>(w2, w3, w4, w2b, w3b, w4b);
  fps_morton_kernel<<<B_, 256, 0, stream>>>(xyz, centers_ord);
  knn_kernel       <<<dim3(G_, B_), 256, 0, stream>>>(xyz, centers_ord, neigh);
  enc_kernel       <<<dim3(G_, B_), 256, 0, stream>>>(neigh, centers_ord,
      w1, b1, g1, bt1, m1, v1, w2b, b2, w3b, b3, g3, bt3, m3, v3, w4b, b4,
      (float*)d_out);
}